// Round 8
// baseline (98.271 us; speedup 1.0000x reference)
//
#include <hip/hip_runtime.h>
#include <math.h>

#define NC    10
#define BATCH 256
#define IC    1152
#define LDIM  8
#define OC    16

#define NCH   96
#define CH    (IC/NCH)        // 12 i's per block
#define NBLK  (NC*NCH)        // 960 blocks, %8==0 -> bijective XCD swizzle
#define NTHR  256
#define NTOT  (NC*BATCH*OC)   // 40960
#define NRED  (NTOT/NTHR)     // 160 reduction blocks

typedef float f32x2 __attribute__((ext_vector_type(2)));

__device__ __forceinline__ int xcd_swizzle(int bid, int nwg) {
    int cpx = nwg >> 3;
    return (bid & 7) * cpx + (bid >> 3);
}

// ---------------------------------------------------------------------------
// K0: transpose x[b][i][l] -> xT[i][b][l] (coalesced thread=b loads later)
// ---------------------------------------------------------------------------
__global__ __launch_bounds__(256) void k0_xT(const float* __restrict__ x,
                                             float* __restrict__ xT)
{
    int u = blockIdx.x * 256 + threadIdx.x;       // < 589824
    int i = u >> 9, r = u & 511, b = r >> 1, h = r & 1;
    reinterpret_cast<float4*>(xT)[u] =
        reinterpret_cast<const float4*>(x)[((size_t)b * IC + i) * 2 + h];
}

// ---------------------------------------------------------------------------
// KA: iter-0 s partials. c uniform = 1/256 -> s0_part = (1/256) * sum_i p.
// thread = b; w lane-uniform (scalar loads); xT coalesced; packed fp32 FMA.
// ---------------------------------------------------------------------------
__global__ __launch_bounds__(256) void kA(
    const float* __restrict__ xT, const float* __restrict__ w,
    float* __restrict__ s_part)
{
    int wg = xcd_swizzle(blockIdx.x, NBLK);
    int n  = wg / NCH, ch = wg % NCH;
    int i0 = ch * CH;
    int t  = threadIdx.x;            // = b

    f32x2 sp2[8];
#pragma unroll
    for (int j = 0; j < 8; ++j) sp2[j] = (f32x2){0.f, 0.f};

    for (int ii = 0; ii < CH; ++ii) {
        int i = i0 + ii;
        const float4* xp = reinterpret_cast<const float4*>(xT)
                         + ((size_t)i * BATCH + t) * 2;
        float4 xa = xp[0], xb = xp[1];
        float xr[8] = {xa.x, xa.y, xa.z, xa.w, xb.x, xb.y, xb.z, xb.w};
        const f32x2* wp2 = reinterpret_cast<const f32x2*>(
            w + (size_t)__builtin_amdgcn_readfirstlane((n * IC + i) * (LDIM * OC)));
#pragma unroll
        for (int l = 0; l < LDIM; ++l) {
            f32x2 xl = {xr[l], xr[l]};
#pragma unroll
            for (int j = 0; j < 8; ++j)
                sp2[j] += wp2[l * 8 + j] * xl;    // v_pk_fma_f32
        }
    }
    float4* dst = reinterpret_cast<float4*>(s_part)
                + (((size_t)ch * NC + n) * BATCH + t) * 4;
    const float inv = 1.0f / 256.0f;
    dst[0] = make_float4(sp2[0].x*inv, sp2[0].y*inv, sp2[1].x*inv, sp2[1].y*inv);
    dst[1] = make_float4(sp2[2].x*inv, sp2[2].y*inv, sp2[3].x*inv, sp2[3].y*inv);
    dst[2] = make_float4(sp2[4].x*inv, sp2[4].y*inv, sp2[5].x*inv, sp2[5].y*inv);
    dst[3] = make_float4(sp2[6].x*inv, sp2[6].y*inv, sp2[7].x*inv, sp2[7].y*inv);
}

// ---------------------------------------------------------------------------
// KR: s[idx] = sum_ch s_part[ch][idx]; per-block n2 partial (fixed order)
// ---------------------------------------------------------------------------
__global__ __launch_bounds__(256) void kR(const float* __restrict__ s_part,
                                          float* __restrict__ s,
                                          float* __restrict__ n2_part)
{
    int idx = blockIdx.x * 256 + threadIdx.x;    // 160 blocks exactly
    float acc = 0.f;
    for (int c2 = 0; c2 < NCH; ++c2) acc += s_part[(size_t)c2 * NTOT + idx];
    s[idx] = acc;
    float q = acc * acc;
#pragma unroll
    for (int m = 32; m >= 1; m >>= 1) q += __shfl_xor(q, m, 64);
    __shared__ float r[4];
    int lane = threadIdx.x & 63, wid = threadIdx.x >> 6;
    if (lane == 0) r[wid] = q;
    __syncthreads();
    if (threadIdx.x == 0) n2_part[blockIdx.x] = r[0] + r[1] + r[2] + r[3];
}

// ---------------------------------------------------------------------------
// KB: one fused routing step. Per i: p = priors(:,i), beta = p.v (+old),
//     in-block softmax over b -> c, s_part += c*p. Packed fp32 FMA throughout.
// ---------------------------------------------------------------------------
template<bool FIRST>
__global__ __launch_bounds__(256) void kB(
    const float* __restrict__ xT, const float* __restrict__ w,
    const float* __restrict__ s, const float* __restrict__ n2_part,
    float* __restrict__ betaT, float* __restrict__ s_part)
{
    __shared__ float redA[2][4];
    __shared__ float redW[4];
    int t = threadIdx.x, lane = t & 63, wid = t >> 6;
    int wg = xcd_swizzle(blockIdx.x, NBLK);
    int n  = wg / NCH, ch = wg % NCH;
    int i0 = ch * CH;

    // squash scale from n2 partials (redundant per block, fixed order)
    float q = (t < NRED) ? n2_part[t] : 0.f;
#pragma unroll
    for (int m = 32; m >= 1; m >>= 1) q += __shfl_xor(q, m, 64);
    if (lane == 0) redW[wid] = q;
    __syncthreads();
    float n2 = redW[0] + redW[1] + redW[2] + redW[3];
    float sc = sqrtf(n2) / (1.0f + n2);

    // v[n,b,:] = s * scale (packed)
    f32x2 v2[8];
    {
        const f32x2* svp = reinterpret_cast<const f32x2*>(s)
                         + ((size_t)n * BATCH + t) * 8;
        f32x2 scv = {sc, sc};
#pragma unroll
        for (int j = 0; j < 8; ++j) v2[j] = svp[j] * scv;
    }

    f32x2 sp2[8];
#pragma unroll
    for (int j = 0; j < 8; ++j) sp2[j] = (f32x2){0.f, 0.f};

    for (int ii = 0; ii < CH; ++ii) {
        int i = i0 + ii;
        const float4* xp = reinterpret_cast<const float4*>(xT)
                         + ((size_t)i * BATCH + t) * 2;
        float4 xa = xp[0], xb = xp[1];
        float xr[8] = {xa.x, xa.y, xa.z, xa.w, xb.x, xb.y, xb.z, xb.w};
        const f32x2* wp2 = reinterpret_cast<const f32x2*>(
            w + (size_t)__builtin_amdgcn_readfirstlane((n * IC + i) * (LDIM * OC)));

        f32x2 p2[8];
#pragma unroll
        for (int j = 0; j < 8; ++j) p2[j] = (f32x2){0.f, 0.f};
#pragma unroll
        for (int l = 0; l < LDIM; ++l) {
            f32x2 xl = {xr[l], xr[l]};
#pragma unroll
            for (int j = 0; j < 8; ++j)
                p2[j] += wp2[l * 8 + j] * xl;     // v_pk_fma_f32
        }

        f32x2 d2 = p2[0] * v2[0];
#pragma unroll
        for (int j = 1; j < 8; ++j) d2 += p2[j] * v2[j];
        float dot = d2.x + d2.y;

        size_t bidx = ((size_t)n * IC + i) * BATCH + t;   // coalesced
        float beta;
        if (FIRST) { beta = dot; betaT[bidx] = beta; }
        else       { beta = betaT[bidx] + dot; }

        // in-block softmax over b: exp-sum across 4 waves (dbl-buffered LDS)
        float e = __expf(beta);
        float es = e;
#pragma unroll
        for (int m = 1; m < 64; m <<= 1) es += __shfl_xor(es, m, 64);
        if (lane == 0) redA[ii & 1][wid] = es;
        __syncthreads();
        float denom = redA[ii & 1][0] + redA[ii & 1][1]
                    + redA[ii & 1][2] + redA[ii & 1][3];
        float c = e * (1.0f / denom);
        f32x2 c2 = {c, c};
#pragma unroll
        for (int j = 0; j < 8; ++j) sp2[j] += c2 * p2[j];
    }

    float4* dst = reinterpret_cast<float4*>(s_part)
                + (((size_t)ch * NC + n) * BATCH + t) * 4;
    dst[0] = make_float4(sp2[0].x, sp2[0].y, sp2[1].x, sp2[1].y);
    dst[1] = make_float4(sp2[2].x, sp2[2].y, sp2[3].x, sp2[3].y);
    dst[2] = make_float4(sp2[4].x, sp2[4].y, sp2[5].x, sp2[5].y);
    dst[3] = make_float4(sp2[6].x, sp2[6].y, sp2[7].x, sp2[7].y);
}

// ---------------------------------------------------------------------------
// K_OUT: scale from n2 partials; out = s * scale
// ---------------------------------------------------------------------------
__global__ __launch_bounds__(256) void k_out(const float* __restrict__ s,
                                             const float* __restrict__ n2_part,
                                             float* __restrict__ out)
{
    int t = threadIdx.x, lane = t & 63, wid = t >> 6;
    float q = (t < NRED) ? n2_part[t] : 0.f;
#pragma unroll
    for (int m = 32; m >= 1; m >>= 1) q += __shfl_xor(q, m, 64);
    __shared__ float r[4];
    if (lane == 0) r[wid] = q;
    __syncthreads();
    float n2 = r[0] + r[1] + r[2] + r[3];
    float sc = sqrtf(n2) / (1.0f + n2);
    int idx = blockIdx.x * 256 + t;
    out[idx] = s[idx] * sc;
}

// ---------------------------------------------------------------------------
extern "C" void kernel_launch(void* const* d_in, const int* in_sizes, int n_in,
                              void* d_out, int out_size, void* d_ws, size_t ws_size,
                              hipStream_t stream)
{
    const float* x = (const float*)d_in[0];   // [256,1152,8]
    const float* w = (const float*)d_in[1];   // [10,1152,8,16]
    float* out = (float*)d_out;               // 40960 floats
    float* ws  = (float*)d_ws;

    float* xT      = ws;                                        // 2,359,296
    float* betaT   = xT + (size_t)IC * BATCH * LDIM;            // 2,949,120
    float* s       = betaT + (size_t)NC * IC * BATCH;           //    40,960
    float* s_part  = s + (size_t)NC * BATCH * OC;               // 3,932,160
    float* n2_part = s_part + (size_t)NCH * NC * BATCH * OC;    //       160
    // total ~37 MB of workspace

    dim3 blk(256);

    k0_xT<<<2304, blk, 0, stream>>>(x, xT);
    // iter 1: c uniform
    kA<<<NBLK, blk, 0, stream>>>(xT, w, s_part);
    kR<<<NRED, blk, 0, stream>>>(s_part, s, n2_part);
    // iter 2 fused: beta1 = p.v0, softmax, s1
    kB<true><<<NBLK, blk, 0, stream>>>(xT, w, s, n2_part, betaT, s_part);
    kR<<<NRED, blk, 0, stream>>>(s_part, s, n2_part);
    // iter 3 fused: beta2 = beta1 + p.v1, softmax, s2
    kB<false><<<NBLK, blk, 0, stream>>>(xT, w, s, n2_part, betaT, s_part);
    kR<<<NRED, blk, 0, stream>>>(s_part, s, n2_part);
    // final squash -> out
    k_out<<<NRED, blk, 0, stream>>>(s, n2_part, out);
}